// Round 19
// baseline (1102.080 us; speedup 1.0000x reference)
//
#include <hip/hip_runtime.h>
#include <hip/hip_bf16.h>
#include <hip/hip_fp8.h>

#define EPS 1e-5f

typedef short bf16x8 __attribute__((ext_vector_type(8)));
typedef short short4v __attribute__((ext_vector_type(4)));
typedef short short16v __attribute__((ext_vector_type(16)));
typedef float f32x4 __attribute__((ext_vector_type(4)));
typedef float f32x2 __attribute__((ext_vector_type(2)));
typedef unsigned char uchar16v __attribute__((ext_vector_type(16)));

static __device__ __forceinline__ short f2bf(float x) {
    __hip_bfloat16 h = __float2bfloat16(x);
    return *reinterpret_cast<short*>(&h);
}
static __device__ __forceinline__ float bf2f(short x) {
    __hip_bfloat16 h;
    *reinterpret_cast<short*>(&h) = x;
    return __bfloat162float(h);
}
static __device__ __forceinline__ unsigned char f2fp8(float x) {
    __hip_fp8_e4m3 q(x);
    return (unsigned char)q.__x;
}
static __device__ __forceinline__ float fp82f(unsigned char b) {
    __hip_fp8_e4m3 q;
    q.__x = (__hip_fp8_storage_t)b;
    return (float)q;
}
static __device__ __forceinline__ unsigned pack4_fp8(float v0, float v1, float v2, float v3) {
#if __has_builtin(__builtin_amdgcn_cvt_pk_fp8_f32)
    int pk = __builtin_amdgcn_cvt_pk_fp8_f32(v0, v1, 0, false);
    pk = __builtin_amdgcn_cvt_pk_fp8_f32(v2, v3, pk, true);
    return (unsigned)pk;
#else
    return (unsigned)f2fp8(v0) | ((unsigned)f2fp8(v1) << 8) |
           ((unsigned)f2fp8(v2) << 16) | ((unsigned)f2fp8(v3) << 24);
#endif
}
template<bool HI>
static __device__ __forceinline__ f32x2 unpack2_fp8(int w) {
#if __has_builtin(__builtin_amdgcn_cvt_pk_f32_fp8)
    return __builtin_amdgcn_cvt_pk_f32_fp8(w, HI);
#else
    f32x2 r;
    const int sh = HI ? 16 : 0;
    r[0] = fp82f((unsigned char)((w >> sh) & 0xff));
    r[1] = fp82f((unsigned char)((w >> (sh + 8)) & 0xff));
    return r;
#endif
}

// ========== split-bf16 MFMA GEMM: C = act(A[M,K](f32) @ BT[N,K]^T + bias) ==========
template<int SPLIT, int ACT, int OUTM>
__global__ __launch_bounds__(256) void gemm_split(const float* __restrict__ A,
                                                  const short* __restrict__ BTh,
                                                  const short* __restrict__ BTl,
                                                  const float* __restrict__ bias,
                                                  void* __restrict__ Cout,
                                                  void* __restrict__ Cout2,
                                                  int M, int N, int K) {
    __shared__ short Ah[128][40];
    __shared__ short Al[128][40];
    __shared__ short Bh[128][40];
    __shared__ short Bl[128][40];
    const int tid = threadIdx.x;
    const int row0 = blockIdx.y * 128, col0 = blockIdx.x * 128;
    const int lane = tid & 63, w = tid >> 6;
    const int wr = w >> 1, wc = w & 1;
    const int lr = lane & 15, lg = lane >> 4;
    f32x4 acc[4][4] = {};

    for (int k0 = 0; k0 < K; k0 += 32) {
        #pragma unroll
        for (int i = 0; i < 4; ++i) {
            int idx = i * 256 + tid;
            int r = idx >> 3, q = idx & 7;
            int gr = row0 + r, gk = k0 + q * 4;
            f32x4 v;
            if (gr < M && gk + 3 < K) {
                v = *reinterpret_cast<const f32x4*>(&A[(size_t)gr * K + gk]);
            } else {
                #pragma unroll
                for (int j = 0; j < 4; ++j)
                    v[j] = (gr < M && gk + j < K) ? A[(size_t)gr * K + gk + j] : 0.f;
            }
            short4v h, l;
            #pragma unroll
            for (int j = 0; j < 4; ++j) {
                h[j] = f2bf(v[j]);
                l[j] = f2bf(v[j] - bf2f(h[j]));
            }
            *reinterpret_cast<short4v*>(&Ah[r][q * 4]) = h;
            *reinterpret_cast<short4v*>(&Al[r][q * 4]) = l;
        }
        #pragma unroll
        for (int i = 0; i < 4; ++i) {
            int idx = i * 256 + tid;
            int r = idx >> 3, q = idx & 7;
            int gc = col0 + r, gk = k0 + q * 4;
            short4v u, ul;
            if (gk + 3 < K) {
                u = *reinterpret_cast<const short4v*>(&BTh[(size_t)gc * K + gk]);
                if (SPLIT == 3) ul = *reinterpret_cast<const short4v*>(&BTl[(size_t)gc * K + gk]);
            } else {
                #pragma unroll
                for (int j = 0; j < 4; ++j) {
                    u[j] = (gk + j < K) ? BTh[(size_t)gc * K + gk + j] : (short)0;
                    if (SPLIT == 3) ul[j] = (gk + j < K) ? BTl[(size_t)gc * K + gk + j] : (short)0;
                }
            }
            *reinterpret_cast<short4v*>(&Bh[r][q * 4]) = u;
            if (SPLIT == 3) *reinterpret_cast<short4v*>(&Bl[r][q * 4]) = ul;
        }
        __syncthreads();
        bf16x8 afh[4], afl[4], bfh[4];
        #pragma unroll
        for (int mi = 0; mi < 4; ++mi) {
            afh[mi] = *reinterpret_cast<const bf16x8*>(&Ah[wr * 64 + mi * 16 + lr][lg * 8]);
            afl[mi] = *reinterpret_cast<const bf16x8*>(&Al[wr * 64 + mi * 16 + lr][lg * 8]);
        }
        #pragma unroll
        for (int ni = 0; ni < 4; ++ni)
            bfh[ni] = *reinterpret_cast<const bf16x8*>(&Bh[wc * 64 + ni * 16 + lr][lg * 8]);
        #pragma unroll
        for (int mi = 0; mi < 4; ++mi)
            #pragma unroll
            for (int ni = 0; ni < 4; ++ni) {
                acc[mi][ni] = __builtin_amdgcn_mfma_f32_16x16x32_bf16(afh[mi], bfh[ni], acc[mi][ni], 0, 0, 0);
                acc[mi][ni] = __builtin_amdgcn_mfma_f32_16x16x32_bf16(afl[mi], bfh[ni], acc[mi][ni], 0, 0, 0);
            }
        if (SPLIT == 3) {
            bf16x8 bfl[4];
            #pragma unroll
            for (int ni = 0; ni < 4; ++ni)
                bfl[ni] = *reinterpret_cast<const bf16x8*>(&Bl[wc * 64 + ni * 16 + lr][lg * 8]);
            #pragma unroll
            for (int mi = 0; mi < 4; ++mi)
                #pragma unroll
                for (int ni = 0; ni < 4; ++ni)
                    acc[mi][ni] = __builtin_amdgcn_mfma_f32_16x16x32_bf16(afh[mi], bfl[ni], acc[mi][ni], 0, 0, 0);
        }
        __syncthreads();
    }

    #pragma unroll
    for (int mi = 0; mi < 4; ++mi) {
        #pragma unroll
        for (int ni = 0; ni < 4; ++ni) {
            int col = col0 + wc * 64 + ni * 16 + lr;
            float bv = bias ? bias[col] : 0.f;
            #pragma unroll
            for (int r = 0; r < 4; ++r) {
                int row = row0 + wr * 64 + mi * 16 + lg * 4 + r;
                if (row >= M) continue;
                float v = acc[mi][ni][r] + bv;
                if (ACT) v = fmaxf(v, 0.f);
                if (OUTM == 0) ((float*)Cout)[(size_t)row * N + col] = v;
                else ((short*)Cout)[(size_t)row * N + col] = f2bf(v);
            }
        }
    }
}

// ========== ep GEMM: ep[M,128] = ea1[M,128] @ wnT^T, 64-row tiles, B staged once ==========
__global__ __launch_bounds__(256) void ep_gemm64(const short* __restrict__ A,
                                                 const short* __restrict__ BT,
                                                 short* __restrict__ Cout, int M) {
    __shared__ short Bf[128 * 136];
    __shared__ short As[64 * 40];
    const int tid = threadIdx.x;
    const int row0 = blockIdx.x * 64;
    const int lane = tid & 63, w = tid >> 6;
    const int lr = lane & 15, lg = lane >> 4;

    #pragma unroll
    for (int i = 0; i < 8; ++i) {
        int idx = i * 256 + tid;
        int r = idx >> 4, q = idx & 15;
        *reinterpret_cast<bf16x8*>(&Bf[r * 136 + q * 8]) =
            *reinterpret_cast<const bf16x8*>(&BT[(size_t)r * 128 + q * 8]);
    }
    __syncthreads();

    f32x4 acc[4][2] = {};
    for (int k0 = 0; k0 < 128; k0 += 32) {
        #pragma unroll
        for (int i = 0; i < 2; ++i) {
            int idx = i * 256 + tid;
            int r = idx >> 3, q = idx & 7;
            int gr = row0 + r;
            short4v v;
            if (gr < M) {
                v = *reinterpret_cast<const short4v*>(&A[(size_t)gr * 128 + k0 + q * 4]);
            } else {
                #pragma unroll
                for (int j = 0; j < 4; ++j) v[j] = 0;
            }
            *reinterpret_cast<short4v*>(&As[r * 40 + q * 4]) = v;
        }
        __syncthreads();
        bf16x8 af[4], bfr[2];
        #pragma unroll
        for (int mi = 0; mi < 4; ++mi)
            af[mi] = *reinterpret_cast<const bf16x8*>(&As[(mi * 16 + lr) * 40 + lg * 8]);
        #pragma unroll
        for (int ni = 0; ni < 2; ++ni)
            bfr[ni] = *reinterpret_cast<const bf16x8*>(&Bf[(w * 32 + ni * 16 + lr) * 136 + k0 + lg * 8]);
        #pragma unroll
        for (int mi = 0; mi < 4; ++mi)
            #pragma unroll
            for (int ni = 0; ni < 2; ++ni)
                acc[mi][ni] = __builtin_amdgcn_mfma_f32_16x16x32_bf16(af[mi], bfr[ni], acc[mi][ni], 0, 0, 0);
        __syncthreads();
    }

    #pragma unroll
    for (int mi = 0; mi < 4; ++mi) {
        #pragma unroll
        for (int ni = 0; ni < 2; ++ni) {
            int col = w * 32 + ni * 16 + lr;
            #pragma unroll
            for (int r = 0; r < 4; ++r) {
                int row = row0 + mi * 16 + lg * 4 + r;
                if (row >= M) continue;
                Cout[(size_t)row * 128 + col] = f2bf(acc[mi][ni][r]);
            }
        }
    }
}

// ========== fused xp + Y kernel v11: 64-row tiles, 8 waves (512 thr) ==========
__global__ __launch_bounds__(512) void fused_xpy(const float* __restrict__ h,
                                                 const short* __restrict__ wnTh,
                                                 const short* __restrict__ wnTl,
                                                 const short* __restrict__ wbBT,
                                                 const float* __restrict__ wl1,
                                                 const float* __restrict__ wl2,
                                                 const float* __restrict__ wlb,
                                                 float* __restrict__ xpf,
                                                 float* __restrict__ ubuf,
                                                 unsigned char* __restrict__ Y,
                                                 float* __restrict__ agg, int M) {
    __shared__ short sbuf[15360];
    __shared__ unsigned char yb[64 * 136];
    short* Ah = sbuf;                 // 64 x 40
    short* Al = sbuf + 2560;
    short* Bh = sbuf + 5120;          // 128 x 40
    short* Bl = sbuf + 10240;
    short* xpH = sbuf;                // 64 x 136 (aliases staging after phase-1 final barrier)

    const int tid = threadIdx.x;
    const int row0 = blockIdx.x * 64;
    const int lane = tid & 63, w = tid >> 6;   // 8 waves, each owns 16 output cols
    const int lr = lane & 15, lg = lane >> 4;

    // ---- zero agg for this block's rows (coalesced 16B stores) ----
    {
        f32x4 z = {0.f, 0.f, 0.f, 0.f};
        #pragma unroll
        for (int i = 0; i < 4; ++i) {
            int chunk = i * 512 + tid;            // 2048 chunks of f32x4
            int flat = chunk * 4;
            int rl = flat >> 7, cs = flat & 127;
            int row = row0 + rl;
            if (row < M)
                *reinterpret_cast<f32x4*>(&agg[(size_t)row * 128 + cs]) = z;
        }
    }

    // ---- phase 1: xp = h @ wnT (split-3) ----
    f32x4 acc1[4] = {};
    for (int k0 = 0; k0 < 128; k0 += 32) {
        {   // A: 64 rows x 8 chunks = 512, one per thread
            int r = tid >> 3, q = tid & 7;
            int gr = row0 + r, gk = k0 + q * 4;
            f32x4 v;
            if (gr < M) {
                v = *reinterpret_cast<const f32x4*>(&h[(size_t)gr * 128 + gk]);
            } else {
                #pragma unroll
                for (int j = 0; j < 4; ++j) v[j] = 0.f;
            }
            short4v hh, ll;
            #pragma unroll
            for (int j = 0; j < 4; ++j) {
                hh[j] = f2bf(v[j]);
                ll[j] = f2bf(v[j] - bf2f(hh[j]));
            }
            *reinterpret_cast<short4v*>(&Ah[r * 40 + q * 4]) = hh;
            *reinterpret_cast<short4v*>(&Al[r * 40 + q * 4]) = ll;
        }
        #pragma unroll
        for (int i = 0; i < 2; ++i) {  // B: 128 rows x 8 chunks = 1024
            int idx = i * 512 + tid;
            int r = idx >> 3, q = idx & 7;
            int gk = k0 + q * 4;
            short4v bh = *reinterpret_cast<const short4v*>(&wnTh[(size_t)r * 128 + gk]);
            short4v bl = *reinterpret_cast<const short4v*>(&wnTl[(size_t)r * 128 + gk]);
            *reinterpret_cast<short4v*>(&Bh[r * 40 + q * 4]) = bh;
            *reinterpret_cast<short4v*>(&Bl[r * 40 + q * 4]) = bl;
        }
        __syncthreads();
        bf16x8 afh[4], afl[4], bfh, bfl;
        #pragma unroll
        for (int mi = 0; mi < 4; ++mi) {
            afh[mi] = *reinterpret_cast<const bf16x8*>(&Ah[(mi * 16 + lr) * 40 + lg * 8]);
            afl[mi] = *reinterpret_cast<const bf16x8*>(&Al[(mi * 16 + lr) * 40 + lg * 8]);
        }
        bfh = *reinterpret_cast<const bf16x8*>(&Bh[(w * 16 + lr) * 40 + lg * 8]);
        bfl = *reinterpret_cast<const bf16x8*>(&Bl[(w * 16 + lr) * 40 + lg * 8]);
        #pragma unroll
        for (int mi = 0; mi < 4; ++mi) {
            acc1[mi] = __builtin_amdgcn_mfma_f32_16x16x32_bf16(afh[mi], bfh, acc1[mi], 0, 0, 0);
            acc1[mi] = __builtin_amdgcn_mfma_f32_16x16x32_bf16(afl[mi], bfh, acc1[mi], 0, 0, 0);
            acc1[mi] = __builtin_amdgcn_mfma_f32_16x16x32_bf16(afh[mi], bfl, acc1[mi], 0, 0, 0);
        }
        __syncthreads();
    }

    // ---- write xp: LDS hi (bf16) + global fp32 ----
    #pragma unroll
    for (int mi = 0; mi < 4; ++mi) {
        int col = w * 16 + lr;
        #pragma unroll
        for (int r = 0; r < 4; ++r) {
            int rl = mi * 16 + lg * 4 + r;
            float v = acc1[mi][r];
            xpH[rl * 136 + col] = f2bf(v);
            int row = row0 + rl;
            if (row < M) xpf[(size_t)row * 128 + col] = v;
        }
    }
    __syncthreads();

    // ---- u = xp_hi . wl2 + wlb (512 outputs, one per thread) ----
    {
        int rl = tid >> 3, s = tid & 7;
        int row = row0 + rl;
        if (row < M) {
            float p = wlb[s];
            #pragma unroll
            for (int j = 0; j < 16; ++j) {
                bf16x8 xv = *reinterpret_cast<const bf16x8*>(&xpH[rl * 136 + j * 8]);
                #pragma unroll
                for (int k = 0; k < 8; ++k)
                    p += bf2f(xv[k]) * wl2[(j * 8 + k) * 8 + s];
            }
            ubuf[(size_t)row * 8 + s] = p;
        }
    }

    // ---- phase 2 (transposed operands): each wave 16 Y cols per ct ----
    for (int ct = 0; ct < 8; ++ct) {
        f32x4 accT[4] = {};
        #pragma unroll
        for (int k = 0; k < 4; ++k) {
            int col = ct * 128 + w * 16 + lr;
            bf16x8 bfr = *reinterpret_cast<const bf16x8*>(&wbBT[(size_t)col * 128 + k * 32 + lg * 8]);
            bf16x8 ah[4];
            #pragma unroll
            for (int mi = 0; mi < 4; ++mi)
                ah[mi] = *reinterpret_cast<const bf16x8*>(&xpH[(mi * 16 + lr) * 136 + k * 32 + lg * 8]);
            #pragma unroll
            for (int mi = 0; mi < 4; ++mi)
                accT[mi] = __builtin_amdgcn_mfma_f32_16x16x32_bf16(bfr, ah[mi], accT[mi], 0, 0, 0);
        }
        {
            int colg = w * 16 + lg * 4;
            #pragma unroll
            for (int mi = 0; mi < 4; ++mi) {
                unsigned pk = pack4_fp8(accT[mi][0] + wl1[(colg + 0) * 8 + ct],
                                        accT[mi][1] + wl1[(colg + 1) * 8 + ct],
                                        accT[mi][2] + wl1[(colg + 2) * 8 + ct],
                                        accT[mi][3] + wl1[(colg + 3) * 8 + ct]);
                *reinterpret_cast<unsigned*>(&yb[(mi * 16 + lr) * 136 + colg]) = pk;
            }
        }
        __syncthreads();
        {   // coalesced store: 8KB tile, 512 threads x 16B
            int rl = tid >> 3;
            int cs = (tid & 7) * 16;
            int row = row0 + rl;
            if (row < M) {
                uchar16v vv = *reinterpret_cast<const uchar16v*>(&yb[rl * 136 + cs]);
                *reinterpret_cast<uchar16v*>(&Y[(size_t)row * 1024 + ct * 128 + cs]) = vv;
            }
        }
        __syncthreads();
    }
}

// ========== fused edge kernel v7: 2 edges/wave for load ILP ==========
__global__ __launch_bounds__(256) void edge_fused3(const float* __restrict__ xpf,
                                                   const short* __restrict__ ep,
                                                   const unsigned char* __restrict__ Y,
                                                   const int* __restrict__ ei,
                                                   const float* __restrict__ u,
                                                   const float* __restrict__ wl2g,
                                                   float* __restrict__ agg, int E) {
    __shared__ float swl[128][9];
    for (int i = threadIdx.x; i < 1024; i += 256) swl[i >> 3][i & 7] = wl2g[i];
    __syncthreads();
    int w = threadIdx.x >> 6;
    int l = threadIdx.x & 63;
    int s = l & 7, c0 = (l >> 3) * 16;
    int e0 = blockIdx.x * 8 + w;
    int e1 = e0 + 4;
    bool ok0 = e0 < E, ok1 = e1 < E;
    int src0 = ok0 ? ei[e0] : 0, dst0 = ok0 ? ei[E + e0] : 0;
    int src1 = ok1 ? ei[e1] : 0, dst1 = ok1 ? ei[E + e1] : 0;

    uchar16v yv0 = *reinterpret_cast<const uchar16v*>(Y + (size_t)src0 * 1024 + s * 128 + c0);
    uchar16v yv1 = *reinterpret_cast<const uchar16v*>(Y + (size_t)src1 * 1024 + s * 128 + c0);
    const float* xi0 = xpf + (size_t)dst0 * 128 + c0;
    const float* xi1 = xpf + (size_t)dst1 * 128 + c0;
    f32x4 xa0 = *reinterpret_cast<const f32x4*>(xi0);
    f32x4 xb0 = *reinterpret_cast<const f32x4*>(xi0 + 4);
    f32x4 xc0 = *reinterpret_cast<const f32x4*>(xi0 + 8);
    f32x4 xd0 = *reinterpret_cast<const f32x4*>(xi0 + 12);
    f32x4 xa1 = *reinterpret_cast<const f32x4*>(xi1);
    f32x4 xb1 = *reinterpret_cast<const f32x4*>(xi1 + 4);
    f32x4 xc1 = *reinterpret_cast<const f32x4*>(xi1 + 8);
    f32x4 xd1 = *reinterpret_cast<const f32x4*>(xi1 + 12);
    short16v ev0 = *reinterpret_cast<const short16v*>(ep + (size_t)e0 * 128 + c0);
    short16v ev1 = *reinterpret_cast<const short16v*>(ep + (size_t)(ok1 ? e1 : e0) * 128 + c0);
    float xj00 = xpf[(size_t)src0 * 128 + l];
    float xj01 = xpf[(size_t)src0 * 128 + l + 64];
    float xj10 = xpf[(size_t)src1 * 128 + l];
    float xj11 = xpf[(size_t)src1 * 128 + l + 64];
    float u0 = u[(size_t)src0 * 8 + s];
    float u1 = u[(size_t)src1 * 8 + s];
    float em00 = bf2f(ep[(size_t)e0 * 128 + l]);
    float em01 = bf2f(ep[(size_t)e0 * 128 + l + 64]);
    float em10 = bf2f(ep[(size_t)(ok1 ? e1 : e0) * 128 + l]);
    float em11 = bf2f(ep[(size_t)(ok1 ? e1 : e0) * 128 + l + 64]);

    const int* yw0 = reinterpret_cast<const int*>(&yv0);
    const int* yw1 = reinterpret_cast<const int*>(&yv1);
    float p0 = 0.f, p1 = 0.f;
    #pragma unroll
    for (int q = 0; q < 4; ++q) {
        f32x2 a0 = unpack2_fp8<false>(yw0[q]);
        f32x2 b0 = unpack2_fp8<true>(yw0[q]);
        f32x2 a1 = unpack2_fp8<false>(yw1[q]);
        f32x2 b1 = unpack2_fp8<true>(yw1[q]);
        const f32x4* xq0 = (q == 0) ? &xa0 : (q == 1) ? &xb0 : (q == 2) ? &xc0 : &xd0;
        const f32x4* xq1 = (q == 0) ? &xa1 : (q == 1) ? &xb1 : (q == 2) ? &xc1 : &xd1;
        p0 += (*xq0)[0] * a0[0] + (*xq0)[1] * a0[1] + (*xq0)[2] * b0[0] + (*xq0)[3] * b0[1];
        p1 += (*xq1)[0] * a1[0] + (*xq1)[1] * a1[1] + (*xq1)[2] * b1[0] + (*xq1)[3] * b1[1];
    }
    #pragma unroll
    for (int j = 0; j < 8; ++j) {
        float w0 = swl[c0 + j][s], w1 = swl[c0 + 8 + j][s];
        p0 += bf2f(ev0[j]) * w0 + bf2f(ev0[8 + j]) * w1;
        p1 += bf2f(ev1[j]) * w0 + bf2f(ev1[8 + j]) * w1;
    }
    p0 += __shfl_xor(p0, 8); p0 += __shfl_xor(p0, 16); p0 += __shfl_xor(p0, 32);
    p1 += __shfl_xor(p1, 8); p1 += __shfl_xor(p1, 16); p1 += __shfl_xor(p1, 32);
    float alpha0 = tanhf(p0 + u0);
    float alpha1 = tanhf(p1 + u1);
    float a00 = __shfl(alpha0, l >> 4);
    float a01 = __shfl(alpha0, 4 + (l >> 4));
    float a10 = __shfl(alpha1, l >> 4);
    float a11 = __shfl(alpha1, 4 + (l >> 4));
    if (ok0) {
        atomicAdd(&agg[(size_t)dst0 * 128 + l],      fmaxf(xj00, em00) * a00);
        atomicAdd(&agg[(size_t)dst0 * 128 + l + 64], fmaxf(xj01, em01) * a01);
    }
    if (ok1) {
        atomicAdd(&agg[(size_t)dst1 * 128 + l],      fmaxf(xj10, em10) * a10);
        atomicAdd(&agg[(size_t)dst1 * 128 + l + 64], fmaxf(xj11, em11) * a11);
    }
}

// ========== gate GEMM v2: 64-row tiles, split-3, K=256 combined, in place ==========
__global__ __launch_bounds__(256) void gate_gemm_split(float* __restrict__ h,
                                                       const float* __restrict__ aggv,
                                                       const short* __restrict__ BTh,
                                                       const short* __restrict__ BTl,
                                                       const float* __restrict__ gb,
                                                       int M) {
    __shared__ short Ah[64][40];
    __shared__ short Al[64][40];
    __shared__ short Bh[128][40];
    __shared__ short Bl[128][40];
    const int tid = threadIdx.x;
    const int row0 = blockIdx.x * 64;
    const int lane = tid & 63, w = tid >> 6;
    const int lr = lane & 15, lg = lane >> 4;
    f32x4 acc[4][2] = {};

    for (int k0 = 0; k0 < 256; k0 += 32) {
        int sec = k0 >> 7;
        #pragma unroll
        for (int i = 0; i < 2; ++i) {
            int idx = i * 256 + tid;
            int r = idx >> 3, q = idx & 7;
            int gr = row0 + r;
            int ks = (k0 & 127) + q * 4;
            f32x4 v;
            if (gr < M) {
                if (sec == 0) {
                    v = *reinterpret_cast<const f32x4*>(&h[(size_t)gr * 128 + ks]);
                } else {
                    f32x4 a = *reinterpret_cast<const f32x4*>(&aggv[(size_t)gr * 128 + ks]);
                    #pragma unroll
                    for (int j = 0; j < 4; ++j) v[j] = fmaxf(a[j], 0.f);
                }
            } else {
                #pragma unroll
                for (int j = 0; j < 4; ++j) v[j] = 0.f;
            }
            short4v hh, ll;
            #pragma unroll
            for (int j = 0; j < 4; ++j) {
                hh[j] = f2bf(v[j]);
                ll[j] = f2bf(v[j] - bf2f(hh[j]));
            }
            *reinterpret_cast<short4v*>(&Ah[r][q * 4]) = hh;
            *reinterpret_cast<short4v*>(&Al[r][q * 4]) = ll;
        }
        #pragma unroll
        for (int i = 0; i < 4; ++i) {
            int idx = i * 256 + tid;
            int r = idx >> 3, q = idx & 7;
            short4v uu = *reinterpret_cast<const short4v*>(&BTh[(size_t)r * 256 + k0 + q * 4]);
            short4v ul = *reinterpret_cast<const short4v*>(&BTl[(size_t)r * 256 + k0 + q * 4]);
            *reinterpret_cast<short4v*>(&Bh[r][q * 4]) = uu;
            *reinterpret_cast<short4v*>(&Bl[r][q * 4]) = ul;
        }
        __syncthreads();
        bf16x8 afh[4], afl[4], bfh[2], bfl[2];
        #pragma unroll
        for (int mi = 0; mi < 4; ++mi) {
            afh[mi] = *reinterpret_cast<const bf16x8*>(&Ah[mi * 16 + lr][lg * 8]);
            afl[mi] = *reinterpret_cast<const bf16x8*>(&Al[mi * 16 + lr][lg * 8]);
        }
        #pragma unroll
        for (int ni = 0; ni < 2; ++ni) {
            bfh[ni] = *reinterpret_cast<const bf16x8*>(&Bh[w * 32 + ni * 16 + lr][lg * 8]);
            bfl[ni] = *reinterpret_cast<const bf16x8*>(&Bl[w * 32 + ni * 16 + lr][lg * 8]);
        }
        #pragma unroll
        for (int mi = 0; mi < 4; ++mi)
            #pragma unroll
            for (int ni = 0; ni < 2; ++ni) {
                acc[mi][ni] = __builtin_amdgcn_mfma_f32_16x16x32_bf16(afh[mi], bfh[ni], acc[mi][ni], 0, 0, 0);
                acc[mi][ni] = __builtin_amdgcn_mfma_f32_16x16x32_bf16(afl[mi], bfh[ni], acc[mi][ni], 0, 0, 0);
                acc[mi][ni] = __builtin_amdgcn_mfma_f32_16x16x32_bf16(afh[mi], bfl[ni], acc[mi][ni], 0, 0, 0);
            }
        __syncthreads();
    }

    #pragma unroll
    for (int mi = 0; mi < 4; ++mi) {
        #pragma unroll
        for (int ni = 0; ni < 2; ++ni) {
            int col = w * 32 + ni * 16 + lr;
            float gbv = gb[col];
            #pragma unroll
            for (int r = 0; r < 4; ++r) {
                int row = row0 + mi * 16 + lg * 4 + r;
                if (row >= M) continue;
                float beta = fmaxf(acc[mi][ni][r] + gbv, 0.f);
                float hv = h[(size_t)row * 128 + col];
                float hh = fmaxf(aggv[(size_t)row * 128 + col], 0.f);
                h[(size_t)row * 128 + col] = beta * hv + (1.f - beta) * hh;
            }
        }
    }
}

// ========== batch norm ==========
__global__ void bn_stats(const float* __restrict__ z, float* __restrict__ gsum,
                         float* __restrict__ gsq, int M) {
    int c = threadIdx.x & 127;
    int rr = threadIdx.x >> 7;
    float s = 0.f, q = 0.f;
    for (int r = blockIdx.x * 2 + rr; r < M; r += gridDim.x * 2) {
        float v = z[(size_t)r * 128 + c];
        s += v; q += v * v;
    }
    __shared__ float ls[256], lq[256];
    ls[threadIdx.x] = s; lq[threadIdx.x] = q;
    __syncthreads();
    if (threadIdx.x < 128) {
        atomicAdd(&gsum[c], ls[threadIdx.x] + ls[threadIdx.x + 128]);
        atomicAdd(&gsq[c],  lq[threadIdx.x] + lq[threadIdx.x + 128]);
    }
}

__global__ void bn_apply(float* __restrict__ z, const float* __restrict__ gsum,
                         const float* __restrict__ gsq, const float* __restrict__ g,
                         const float* __restrict__ b, int M) {
    size_t total = (size_t)M * 128;
    for (size_t idx = (size_t)blockIdx.x * 256 + threadIdx.x; idx < total;
         idx += (size_t)gridDim.x * 256) {
        int c = idx & 127;
        float mu = gsum[c] / (float)M;
        float var = gsq[c] / (float)M - mu * mu;
        float rs = rsqrtf(var + EPS);
        float v = (z[idx] - mu) * rs * g[c] + b[c];
        z[idx] = fmaxf(v, 0.f);
    }
}

__global__ void bn_stats_bf(const short* __restrict__ z, float* __restrict__ gsum,
                            float* __restrict__ gsq, int M) {
    int c = threadIdx.x & 127;
    int rr = threadIdx.x >> 7;
    float s = 0.f, q = 0.f;
    for (int r = blockIdx.x * 2 + rr; r < M; r += gridDim.x * 2) {
        float v = bf2f(z[(size_t)r * 128 + c]);
        s += v; q += v * v;
    }
    __shared__ float ls[256], lq[256];
    ls[threadIdx.x] = s; lq[threadIdx.x] = q;
    __syncthreads();
    if (threadIdx.x < 128) {
        atomicAdd(&gsum[c], ls[threadIdx.x] + ls[threadIdx.x + 128]);
        atomicAdd(&gsq[c],  lq[threadIdx.x] + lq[threadIdx.x + 128]);
    }
}

__global__ void bn_apply_bf(short* __restrict__ z, const float* __restrict__ gsum,
                            const float* __restrict__ gsq, const float* __restrict__ g,
                            const float* __restrict__ b, int M) {
    size_t total = (size_t)M * 128;
    for (size_t idx = (size_t)blockIdx.x * 256 + threadIdx.x; idx < total;
         idx += (size_t)gridDim.x * 256) {
        int c = idx & 127;
        float mu = gsum[c] / (float)M;
        float var = gsq[c] / (float)M - mu * mu;
        float rs = rsqrtf(var + EPS);
        float v = (bf2f(z[idx]) - mu) * rs * g[c] + b[c];
        z[idx] = f2bf(fmaxf(v, 0.f));
    }
}

// ========== prep ==========
__global__ void transpose_split(const float* __restrict__ in, short* __restrict__ outh,
                                short* __restrict__ outl, int K, int N) {
    int idx = blockIdx.x * 256 + threadIdx.x;
    if (idx >= K * N) return;
    int nI = idx / K, k = idx - nI * K;
    float v = in[(size_t)k * N + nI];
    short h = f2bf(v);
    outh[idx] = h;
    outl[idx] = f2bf(v - bf2f(h));
}

__global__ void cvt_f2b(const float* __restrict__ in, short* __restrict__ out, int n) {
    int i = blockIdx.x * 256 + threadIdx.x;
    if (i < n) out[i] = f2bf(in[i]);
}

__global__ void gate_combine_split(const float* __restrict__ gw, short* __restrict__ BTh,
                                   short* __restrict__ BTl) {
    int idx = blockIdx.x * 256 + threadIdx.x;
    if (idx >= 128 * 256) return;
    int n = idx >> 8, k = idx & 255;
    float v;
    if (k < 128) v = gw[(size_t)k * 128 + n] + gw[(size_t)(256 + k) * 128 + n];
    else {
        int kk = k - 128;
        v = gw[(size_t)(128 + kk) * 128 + n] - gw[(size_t)(256 + kk) * 128 + n];
    }
    short h = f2bf(v);
    BTh[idx] = h;
    BTl[idx] = f2bf(v - bf2f(h));
}

__global__ void build_wm(const float* __restrict__ wsrc, float* __restrict__ wm) {
    int idx = blockIdx.x * 256 + threadIdx.x;
    if (idx >= 128 * 128) return;
    int d = idx >> 7, c = idx & 127;
    float s = 0.f;
    #pragma unroll
    for (int h = 0; h < 8; ++h) s += wsrc[(size_t)d * 1024 + h * 128 + c];
    wm[idx] = s * 0.125f;
}

__global__ void perm_build(const int* __restrict__ ci, int* __restrict__ perm, int NF) {
    int i = blockIdx.x * 256 + threadIdx.x;
    if (i >= NF) return;
    int c = ci[i];
    if (i == 0 || ci[i - 1] != c) perm[c] = i;
}

__global__ void seg_pool(const float* __restrict__ fx, const int* __restrict__ perm,
                         float* __restrict__ pool, int F, int NF) {
    int idx = blockIdx.x * 256 + threadIdx.x;
    if (idx >= F * 128) return;
    int f = idx >> 7, c = idx & 127;
    int s = perm[f];
    int e = (f + 1 < F) ? perm[f + 1] : NF;
    float acc = 0.f;
    for (int i = s; i < e; ++i) acc += fx[(size_t)i * 128 + c];
    pool[idx] = fmaxf(acc, 0.f);
}

// ========== output ==========
__global__ __launch_bounds__(256) void out_phase1(const float* __restrict__ h,
                                                  const float* __restrict__ out_w,
                                                  const float* __restrict__ out_b,
                                                  const float* __restrict__ gat_bias,
                                                  float* __restrict__ out, int M) {
    int n = blockIdx.x * 4 + (threadIdx.x >> 6);
    if (n >= M) return;
    int l = threadIdx.x & 63;
    float p = fmaxf(h[(size_t)n * 128 + l], 0.f) * out_w[l]
            + fmaxf(h[(size_t)n * 128 + l + 64], 0.f) * out_w[l + 64];
    p += fmaxf(gat_bias[l], 0.f) * out_w[128 + l]
       + fmaxf(gat_bias[l + 64], 0.f) * out_w[128 + l + 64];
    #pragma unroll
    for (int off = 32; off; off >>= 1) p += __shfl_xor(p, off);
    if (l == 0) out[n] = p + out_b[0];
}

__global__ __launch_bounds__(256) void out_phase2(const float* __restrict__ fmv,
                                                  const int* __restrict__ perm,
                                                  const float* __restrict__ out_w,
                                                  const float* __restrict__ gat_bias,
                                                  float* __restrict__ out, int F) {
    int f = blockIdx.x * 4 + (threadIdx.x >> 6);
    if (f >= F) return;
    int l = threadIdx.x & 63;
    float p = fmv[(size_t)f * 128 + l] * out_w[128 + l]
            + fmv[(size_t)f * 128 + l + 64] * out_w[128 + l + 64];
    float b = fmaxf(gat_bias[l], 0.f) * out_w[128 + l]
            + fmaxf(gat_bias[l + 64], 0.f) * out_w[128 + l + 64];
    float d = p - b;
    #pragma unroll
    for (int off = 32; off; off >>= 1) d += __shfl_xor(d, off);
    if (l == 0) out[perm[f]] += d;
}

// ========== host ==========
extern "C" void kernel_launch(void* const* d_in, const int* in_sizes, int n_in,
                              void* d_out, int out_size, void* d_ws, size_t ws_size,
                              hipStream_t stream) {
    const int N = 50000, E = 100000, NF = 20000, EF = 40000, F = 10000;

    const float* x          = (const float*)d_in[0];
    const float* edge_attr  = (const float*)d_in[1];
    const float* frag_x     = (const float*)d_in[2];
    const float* frag_ea    = (const float*)d_in[3];
    const float* la_w = (const float*)d_in[4];
    const float* la_b = (const float*)d_in[5];
    const float* lb_w = (const float*)d_in[6];
    const float* lb_b = (const float*)d_in[7];
    const float* bn1_g = (const float*)d_in[8];
    const float* bn1_b = (const float*)d_in[9];
    const float* bn2_g = (const float*)d_in[10];
    const float* bn2_b = (const float*)d_in[11];
    const float* wn = (const float*)d_in[12];
    const float* wb = (const float*)d_in[13];
    const float* wl = (const float*)d_in[14];
    const float* wlb = (const float*)d_in[15];
    const float* gate_w = (const float*)d_in[16];
    const float* gate_b = (const float*)d_in[17];
    const float* gat_wsrc = (const float*)d_in[18];
    const float* gat_bias = (const float*)d_in[22];
    const float* out_w = (const float*)d_in[23];
    const float* out_b = (const float*)d_in[24];
    const int* edge_index = (const int*)d_in[25];
    const int* frag_edge_index = (const int*)d_in[26];
    const int* cluster_index = (const int*)d_in[27];

    char* p = (char*)d_ws;
    auto alloc = [&](size_t bytes) { char* r = p; p += (bytes + 255) & ~(size_t)255; return (void*)r; };
    float* hA    = (float*)alloc((size_t)N * 128 * 4);
    short* ea1   = (short*)alloc((size_t)E * 128 * 2);
    float* xpf   = (float*)alloc((size_t)N * 128 * 4);
    short* ep    = (short*)alloc((size_t)E * 128 * 2);
    unsigned char* Y = (unsigned char*)alloc((size_t)N * 1024);
    float* agg   = (float*)alloc((size_t)N * 128 * 4);
    float* ubuf  = (float*)alloc((size_t)N * 8 * 4);
    short* la_wTh = (short*)alloc(128 * 128 * 2);
    short* la_wTl = (short*)alloc(128 * 128 * 2);
    short* lb_wTh = (short*)alloc(128 * 16 * 2);
    short* lb_wTl = (short*)alloc(128 * 16 * 2);
    short* wnTh   = (short*)alloc(3 * 128 * 128 * 2);
    short* wnTl   = (short*)alloc(3 * 128 * 128 * 2);
    short* wbH    = (short*)alloc(3 * 1024 * 128 * 2);
    short* gate2Th = (short*)alloc(128 * 256 * 2);
    short* gate2Tl = (short*)alloc(128 * 256 * 2);
    float* wmF    = (float*)alloc(128 * 128 * 4);
    short* wmTh   = (short*)alloc(128 * 128 * 2);
    short* wmTl   = (short*)alloc(128 * 128 * 2);
    float* stats  = (float*)alloc(256 * 4);
    char* yq = (char*)Y;
    float* fpool = (float*)yq;              yq += (size_t)F * 128 * 4;
    float* fmv   = (float*)yq;              yq += (size_t)F * 128 * 4;
    int*   perm  = (int*)yq;

    auto cdiv = [](int a, int b) { return (a + b - 1) / b; };

    // ---- weight prep ----
    transpose_split<<<cdiv(128 * 128, 256), 256, 0, stream>>>(la_w, la_wTh, la_wTl, 128, 128);
    transpose_split<<<cdiv(16 * 128, 256), 256, 0, stream>>>(lb_w, lb_wTh, lb_wTl, 16, 128);
    for (int l = 0; l < 3; ++l)
        transpose_split<<<cdiv(128 * 128, 256), 256, 0, stream>>>(
            wn + (size_t)l * 16384, wnTh + (size_t)l * 16384, wnTl + (size_t)l * 16384, 128, 128);
    cvt_f2b<<<cdiv(3 * 1024 * 128, 256), 256, 0, stream>>>(wb, wbH, 3 * 1024 * 128);
    gate_combine_split<<<cdiv(128 * 256, 256), 256, 0, stream>>>(gate_w, gate2Th, gate2Tl);
    build_wm<<<cdiv(128 * 128, 256), 256, 0, stream>>>(gat_wsrc, wmF);
    transpose_split<<<cdiv(128 * 128, 256), 256, 0, stream>>>(wmF, wmTh, wmTl, 128, 128);

    auto run_layer = [&](float* h, const short* ea_buf, const int* ei, int Mn, int Me, int layer) {
        const short* wnTh_l = wnTh + (size_t)layer * 16384;
        const short* wnTl_l = wnTl + (size_t)layer * 16384;
        const short* wb_l   = wbH + (size_t)layer * 131072;
        const float* wl_l   = wl + (size_t)layer * 384 * 8;
        const float* wlb_l  = wlb + (size_t)layer * 8;
        fused_xpy<<<cdiv(Mn, 64), 512, 0, stream>>>(h, wnTh_l, wnTl_l, wb_l, wl_l,
                                                    wl_l + 256 * 8, wlb_l, xpf, ubuf, Y, agg, Mn);
        ep_gemm64<<<cdiv(Me, 64), 256, 0, stream>>>(ea_buf, wnTh_l, ep, Me);
        edge_fused3<<<cdiv(Me, 8), 256, 0, stream>>>(xpf, ep, Y, ei, ubuf, wl_l + 128 * 8, agg, Me);
        gate_gemm_split<<<cdiv(Mn, 64), 256, 0, stream>>>(h, agg, gate2Th, gate2Tl, gate_b, Mn);
    };

    // ---- atom path ----
    gemm_split<3, 0, 0><<<dim3(1, cdiv(N, 128)), 256, 0, stream>>>(x, la_wTh, la_wTl, la_b, hA, nullptr, N, 128, 128);
    hipMemsetAsync(stats, 0, 1024, stream);
    bn_stats<<<256, 256, 0, stream>>>(hA, stats, stats + 128, N);
    bn_apply<<<2048, 256, 0, stream>>>(hA, stats, stats + 128, bn1_g, bn1_b, N);

    gemm_split<3, 0, 1><<<dim3(1, cdiv(E, 128)), 256, 0, stream>>>(edge_attr, lb_wTh, lb_wTl, lb_b, ea1, nullptr, E, 128, 16);
    hipMemsetAsync(stats, 0, 1024, stream);
    bn_stats_bf<<<256, 256, 0, stream>>>(ea1, stats, stats + 128, E);
    bn_apply_bf<<<2048, 256, 0, stream>>>(ea1, stats, stats + 128, bn2_g, bn2_b, E);

    for (int l = 0; l < 3; ++l) run_layer(hA, ea1, edge_index, N, E, l);
    out_phase1<<<cdiv(N, 4), 256, 0, stream>>>(hA, out_w, out_b, gat_bias, (float*)d_out, N);

    // ---- fragment path ----
    gemm_split<3, 1, 0><<<dim3(1, cdiv(NF, 128)), 256, 0, stream>>>(frag_x, la_wTh, la_wTl, la_b, hA, nullptr, NF, 128, 128);

    gemm_split<3, 0, 1><<<dim3(1, cdiv(EF, 128)), 256, 0, stream>>>(frag_ea, lb_wTh, lb_wTl, lb_b, ea1, nullptr, EF, 128, 16);
    hipMemsetAsync(stats, 0, 1024, stream);
    bn_stats_bf<<<256, 256, 0, stream>>>(ea1, stats, stats + 128, EF);
    bn_apply_bf<<<2048, 256, 0, stream>>>(ea1, stats, stats + 128, bn2_g, bn2_b, EF);

    for (int l = 0; l < 3; ++l) run_layer(hA, ea1, frag_edge_index, NF, EF, l);

    perm_build<<<cdiv(NF, 256), 256, 0, stream>>>(cluster_index, perm, NF);
    seg_pool<<<cdiv(F * 128, 256), 256, 0, stream>>>(hA, perm, fpool, F, NF);
    gemm_split<3, 1, 0><<<dim3(1, cdiv(F, 128)), 256, 0, stream>>>(fpool, wmTh, wmTl, gat_bias, fmv, nullptr, F, 128, 128);
    out_phase2<<<cdiv(F, 4), 256, 0, stream>>>(fmv, perm, out_w, gat_bias, (float*)d_out, F);
}

// Round 20
// 1040.519 us; speedup vs baseline: 1.0592x; 1.0592x over previous
//
#include <hip/hip_runtime.h>
#include <hip/hip_bf16.h>
#include <hip/hip_fp8.h>

#define EPS 1e-5f

typedef short bf16x8 __attribute__((ext_vector_type(8)));
typedef short short4v __attribute__((ext_vector_type(4)));
typedef short short16v __attribute__((ext_vector_type(16)));
typedef float f32x4 __attribute__((ext_vector_type(4)));
typedef float f32x2 __attribute__((ext_vector_type(2)));
typedef unsigned char uchar16v __attribute__((ext_vector_type(16)));

static __device__ __forceinline__ short f2bf(float x) {
    __hip_bfloat16 h = __float2bfloat16(x);
    return *reinterpret_cast<short*>(&h);
}
static __device__ __forceinline__ float bf2f(short x) {
    __hip_bfloat16 h;
    *reinterpret_cast<short*>(&h) = x;
    return __bfloat162float(h);
}
static __device__ __forceinline__ unsigned char f2fp8(float x) {
    __hip_fp8_e4m3 q(x);
    return (unsigned char)q.__x;
}
static __device__ __forceinline__ float fp82f(unsigned char b) {
    __hip_fp8_e4m3 q;
    q.__x = (__hip_fp8_storage_t)b;
    return (float)q;
}
static __device__ __forceinline__ unsigned pack4_fp8(float v0, float v1, float v2, float v3) {
#if __has_builtin(__builtin_amdgcn_cvt_pk_fp8_f32)
    int pk = __builtin_amdgcn_cvt_pk_fp8_f32(v0, v1, 0, false);
    pk = __builtin_amdgcn_cvt_pk_fp8_f32(v2, v3, pk, true);
    return (unsigned)pk;
#else
    return (unsigned)f2fp8(v0) | ((unsigned)f2fp8(v1) << 8) |
           ((unsigned)f2fp8(v2) << 16) | ((unsigned)f2fp8(v3) << 24);
#endif
}
template<bool HI>
static __device__ __forceinline__ f32x2 unpack2_fp8(int w) {
#if __has_builtin(__builtin_amdgcn_cvt_pk_f32_fp8)
    return __builtin_amdgcn_cvt_pk_f32_fp8(w, HI);
#else
    f32x2 r;
    const int sh = HI ? 16 : 0;
    r[0] = fp82f((unsigned char)((w >> sh) & 0xff));
    r[1] = fp82f((unsigned char)((w >> (sh + 8)) & 0xff));
    return r;
#endif
}

// ========== split-bf16 MFMA GEMM: C = act(A[M,K](f32) @ BT[N,K]^T + bias) ==========
template<int SPLIT, int ACT, int OUTM>
__global__ __launch_bounds__(256) void gemm_split(const float* __restrict__ A,
                                                  const short* __restrict__ BTh,
                                                  const short* __restrict__ BTl,
                                                  const float* __restrict__ bias,
                                                  void* __restrict__ Cout,
                                                  void* __restrict__ Cout2,
                                                  int M, int N, int K) {
    __shared__ short Ah[128][40];
    __shared__ short Al[128][40];
    __shared__ short Bh[128][40];
    __shared__ short Bl[128][40];
    const int tid = threadIdx.x;
    const int row0 = blockIdx.y * 128, col0 = blockIdx.x * 128;
    const int lane = tid & 63, w = tid >> 6;
    const int wr = w >> 1, wc = w & 1;
    const int lr = lane & 15, lg = lane >> 4;
    f32x4 acc[4][4] = {};

    for (int k0 = 0; k0 < K; k0 += 32) {
        #pragma unroll
        for (int i = 0; i < 4; ++i) {
            int idx = i * 256 + tid;
            int r = idx >> 3, q = idx & 7;
            int gr = row0 + r, gk = k0 + q * 4;
            f32x4 v;
            if (gr < M && gk + 3 < K) {
                v = *reinterpret_cast<const f32x4*>(&A[(size_t)gr * K + gk]);
            } else {
                #pragma unroll
                for (int j = 0; j < 4; ++j)
                    v[j] = (gr < M && gk + j < K) ? A[(size_t)gr * K + gk + j] : 0.f;
            }
            short4v h, l;
            #pragma unroll
            for (int j = 0; j < 4; ++j) {
                h[j] = f2bf(v[j]);
                l[j] = f2bf(v[j] - bf2f(h[j]));
            }
            *reinterpret_cast<short4v*>(&Ah[r][q * 4]) = h;
            *reinterpret_cast<short4v*>(&Al[r][q * 4]) = l;
        }
        #pragma unroll
        for (int i = 0; i < 4; ++i) {
            int idx = i * 256 + tid;
            int r = idx >> 3, q = idx & 7;
            int gc = col0 + r, gk = k0 + q * 4;
            short4v u, ul;
            if (gk + 3 < K) {
                u = *reinterpret_cast<const short4v*>(&BTh[(size_t)gc * K + gk]);
                if (SPLIT == 3) ul = *reinterpret_cast<const short4v*>(&BTl[(size_t)gc * K + gk]);
            } else {
                #pragma unroll
                for (int j = 0; j < 4; ++j) {
                    u[j] = (gk + j < K) ? BTh[(size_t)gc * K + gk + j] : (short)0;
                    if (SPLIT == 3) ul[j] = (gk + j < K) ? BTl[(size_t)gc * K + gk + j] : (short)0;
                }
            }
            *reinterpret_cast<short4v*>(&Bh[r][q * 4]) = u;
            if (SPLIT == 3) *reinterpret_cast<short4v*>(&Bl[r][q * 4]) = ul;
        }
        __syncthreads();
        bf16x8 afh[4], afl[4], bfh[4];
        #pragma unroll
        for (int mi = 0; mi < 4; ++mi) {
            afh[mi] = *reinterpret_cast<const bf16x8*>(&Ah[wr * 64 + mi * 16 + lr][lg * 8]);
            afl[mi] = *reinterpret_cast<const bf16x8*>(&Al[wr * 64 + mi * 16 + lr][lg * 8]);
        }
        #pragma unroll
        for (int ni = 0; ni < 4; ++ni)
            bfh[ni] = *reinterpret_cast<const bf16x8*>(&Bh[wc * 64 + ni * 16 + lr][lg * 8]);
        #pragma unroll
        for (int mi = 0; mi < 4; ++mi)
            #pragma unroll
            for (int ni = 0; ni < 4; ++ni) {
                acc[mi][ni] = __builtin_amdgcn_mfma_f32_16x16x32_bf16(afh[mi], bfh[ni], acc[mi][ni], 0, 0, 0);
                acc[mi][ni] = __builtin_amdgcn_mfma_f32_16x16x32_bf16(afl[mi], bfh[ni], acc[mi][ni], 0, 0, 0);
            }
        if (SPLIT == 3) {
            bf16x8 bfl[4];
            #pragma unroll
            for (int ni = 0; ni < 4; ++ni)
                bfl[ni] = *reinterpret_cast<const bf16x8*>(&Bl[wc * 64 + ni * 16 + lr][lg * 8]);
            #pragma unroll
            for (int mi = 0; mi < 4; ++mi)
                #pragma unroll
                for (int ni = 0; ni < 4; ++ni)
                    acc[mi][ni] = __builtin_amdgcn_mfma_f32_16x16x32_bf16(afh[mi], bfl[ni], acc[mi][ni], 0, 0, 0);
        }
        __syncthreads();
    }

    #pragma unroll
    for (int mi = 0; mi < 4; ++mi) {
        #pragma unroll
        for (int ni = 0; ni < 4; ++ni) {
            int col = col0 + wc * 64 + ni * 16 + lr;
            float bv = bias ? bias[col] : 0.f;
            #pragma unroll
            for (int r = 0; r < 4; ++r) {
                int row = row0 + wr * 64 + mi * 16 + lg * 4 + r;
                if (row >= M) continue;
                float v = acc[mi][ni][r] + bv;
                if (ACT) v = fmaxf(v, 0.f);
                if (OUTM == 0) ((float*)Cout)[(size_t)row * N + col] = v;
                else ((short*)Cout)[(size_t)row * N + col] = f2bf(v);
            }
        }
    }
}

// ========== ep GEMM: ep[M,128] = ea1[M,128] @ wnT^T, 64-row tiles, B staged once ==========
__global__ __launch_bounds__(256) void ep_gemm64(const short* __restrict__ A,
                                                 const short* __restrict__ BT,
                                                 short* __restrict__ Cout, int M) {
    __shared__ short Bf[128 * 136];
    __shared__ short As[64 * 40];
    const int tid = threadIdx.x;
    const int row0 = blockIdx.x * 64;
    const int lane = tid & 63, w = tid >> 6;
    const int lr = lane & 15, lg = lane >> 4;

    #pragma unroll
    for (int i = 0; i < 8; ++i) {
        int idx = i * 256 + tid;
        int r = idx >> 4, q = idx & 15;
        *reinterpret_cast<bf16x8*>(&Bf[r * 136 + q * 8]) =
            *reinterpret_cast<const bf16x8*>(&BT[(size_t)r * 128 + q * 8]);
    }
    __syncthreads();

    f32x4 acc[4][2] = {};
    for (int k0 = 0; k0 < 128; k0 += 32) {
        #pragma unroll
        for (int i = 0; i < 2; ++i) {
            int idx = i * 256 + tid;
            int r = idx >> 3, q = idx & 7;
            int gr = row0 + r;
            short4v v;
            if (gr < M) {
                v = *reinterpret_cast<const short4v*>(&A[(size_t)gr * 128 + k0 + q * 4]);
            } else {
                #pragma unroll
                for (int j = 0; j < 4; ++j) v[j] = 0;
            }
            *reinterpret_cast<short4v*>(&As[r * 40 + q * 4]) = v;
        }
        __syncthreads();
        bf16x8 af[4], bfr[2];
        #pragma unroll
        for (int mi = 0; mi < 4; ++mi)
            af[mi] = *reinterpret_cast<const bf16x8*>(&As[(mi * 16 + lr) * 40 + lg * 8]);
        #pragma unroll
        for (int ni = 0; ni < 2; ++ni)
            bfr[ni] = *reinterpret_cast<const bf16x8*>(&Bf[(w * 32 + ni * 16 + lr) * 136 + k0 + lg * 8]);
        #pragma unroll
        for (int mi = 0; mi < 4; ++mi)
            #pragma unroll
            for (int ni = 0; ni < 2; ++ni)
                acc[mi][ni] = __builtin_amdgcn_mfma_f32_16x16x32_bf16(af[mi], bfr[ni], acc[mi][ni], 0, 0, 0);
        __syncthreads();
    }

    #pragma unroll
    for (int mi = 0; mi < 4; ++mi) {
        #pragma unroll
        for (int ni = 0; ni < 2; ++ni) {
            int col = w * 32 + ni * 16 + lr;
            #pragma unroll
            for (int r = 0; r < 4; ++r) {
                int row = row0 + mi * 16 + lg * 4 + r;
                if (row >= M) continue;
                Cout[(size_t)row * 128 + col] = f2bf(acc[mi][ni][r]);
            }
        }
    }
}

// ========== fused xp + Y kernel v10: fp32 xp, agg zeroing folded in ==========
__global__ __launch_bounds__(256) void fused_xpy(const float* __restrict__ h,
                                                 const short* __restrict__ wnTh,
                                                 const short* __restrict__ wnTl,
                                                 const short* __restrict__ wbBT,
                                                 const float* __restrict__ wl1,
                                                 const float* __restrict__ wl2,
                                                 const float* __restrict__ wlb,
                                                 float* __restrict__ xpf,
                                                 float* __restrict__ ubuf,
                                                 unsigned char* __restrict__ Y,
                                                 float* __restrict__ agg, int M) {
    __shared__ short sbuf[15360];
    __shared__ unsigned char yb[64 * 136];
    short* Ah = sbuf;
    short* Al = sbuf + 2560;
    short* Bh = sbuf + 5120;
    short* Bl = sbuf + 10240;
    short* xpH = sbuf;

    const int tid = threadIdx.x;
    const int row0 = blockIdx.x * 64;
    const int lane = tid & 63, w = tid >> 6;
    const int lr = lane & 15, lg = lane >> 4;

    // ---- zero agg for this block's rows (32KB, coalesced 16B stores) ----
    {
        f32x4 z = {0.f, 0.f, 0.f, 0.f};
        #pragma unroll
        for (int i = 0; i < 8; ++i) {
            int flat = i * 1024 + tid * 4;
            int rl = flat >> 7, cs = flat & 127;
            int row = row0 + rl;
            if (row < M)
                *reinterpret_cast<f32x4*>(&agg[(size_t)row * 128 + cs]) = z;
        }
    }

    // ---- phase 1 ----
    f32x4 acc1[4][2] = {};
    for (int k0 = 0; k0 < 128; k0 += 32) {
        #pragma unroll
        for (int i = 0; i < 2; ++i) {
            int idx = i * 256 + tid;
            int r = idx >> 3, q = idx & 7;
            int gr = row0 + r, gk = k0 + q * 4;
            f32x4 v;
            if (gr < M) {
                v = *reinterpret_cast<const f32x4*>(&h[(size_t)gr * 128 + gk]);
            } else {
                #pragma unroll
                for (int j = 0; j < 4; ++j) v[j] = 0.f;
            }
            short4v hh, ll;
            #pragma unroll
            for (int j = 0; j < 4; ++j) {
                hh[j] = f2bf(v[j]);
                ll[j] = f2bf(v[j] - bf2f(hh[j]));
            }
            *reinterpret_cast<short4v*>(&Ah[r * 40 + q * 4]) = hh;
            *reinterpret_cast<short4v*>(&Al[r * 40 + q * 4]) = ll;
        }
        #pragma unroll
        for (int i = 0; i < 4; ++i) {
            int idx = i * 256 + tid;
            int r = idx >> 3, q = idx & 7;
            int gk = k0 + q * 4;
            short4v bh = *reinterpret_cast<const short4v*>(&wnTh[(size_t)r * 128 + gk]);
            short4v bl = *reinterpret_cast<const short4v*>(&wnTl[(size_t)r * 128 + gk]);
            *reinterpret_cast<short4v*>(&Bh[r * 40 + q * 4]) = bh;
            *reinterpret_cast<short4v*>(&Bl[r * 40 + q * 4]) = bl;
        }
        __syncthreads();
        bf16x8 afh[4], afl[4], bfh[2], bfl[2];
        #pragma unroll
        for (int mi = 0; mi < 4; ++mi) {
            afh[mi] = *reinterpret_cast<const bf16x8*>(&Ah[(mi * 16 + lr) * 40 + lg * 8]);
            afl[mi] = *reinterpret_cast<const bf16x8*>(&Al[(mi * 16 + lr) * 40 + lg * 8]);
        }
        #pragma unroll
        for (int ni = 0; ni < 2; ++ni) {
            bfh[ni] = *reinterpret_cast<const bf16x8*>(&Bh[(w * 32 + ni * 16 + lr) * 40 + lg * 8]);
            bfl[ni] = *reinterpret_cast<const bf16x8*>(&Bl[(w * 32 + ni * 16 + lr) * 40 + lg * 8]);
        }
        #pragma unroll
        for (int mi = 0; mi < 4; ++mi)
            #pragma unroll
            for (int ni = 0; ni < 2; ++ni) {
                acc1[mi][ni] = __builtin_amdgcn_mfma_f32_16x16x32_bf16(afh[mi], bfh[ni], acc1[mi][ni], 0, 0, 0);
                acc1[mi][ni] = __builtin_amdgcn_mfma_f32_16x16x32_bf16(afl[mi], bfh[ni], acc1[mi][ni], 0, 0, 0);
                acc1[mi][ni] = __builtin_amdgcn_mfma_f32_16x16x32_bf16(afh[mi], bfl[ni], acc1[mi][ni], 0, 0, 0);
            }
        __syncthreads();
    }

    // ---- write xp: LDS hi (bf16) + global fp32 ----
    #pragma unroll
    for (int mi = 0; mi < 4; ++mi) {
        #pragma unroll
        for (int ni = 0; ni < 2; ++ni) {
            int col = w * 32 + ni * 16 + lr;
            #pragma unroll
            for (int r = 0; r < 4; ++r) {
                int rl = mi * 16 + lg * 4 + r;
                float v = acc1[mi][ni][r];
                xpH[rl * 136 + col] = f2bf(v);
                int row = row0 + rl;
                if (row < M) xpf[(size_t)row * 128 + col] = v;
            }
        }
    }
    __syncthreads();

    // ---- u = xp_hi . wl2 + wlb ----
    #pragma unroll
    for (int o = tid; o < 512; o += 256) {
        int rl = o >> 3, s = o & 7;
        int row = row0 + rl;
        if (row < M) {
            float p = wlb[s];
            #pragma unroll
            for (int j = 0; j < 16; ++j) {
                bf16x8 xv = *reinterpret_cast<const bf16x8*>(&xpH[rl * 136 + j * 8]);
                #pragma unroll
                for (int k = 0; k < 8; ++k)
                    p += bf2f(xv[k]) * wl2[(j * 8 + k) * 8 + s];
            }
            ubuf[(size_t)row * 8 + s] = p;
        }
    }

    // ---- phase 2 (transposed operands) ----
    for (int ct = 0; ct < 8; ++ct) {
        f32x4 accT[2][4] = {};
        #pragma unroll
        for (int k = 0; k < 4; ++k) {
            bf16x8 bfr[2];
            #pragma unroll
            for (int ni = 0; ni < 2; ++ni) {
                int col = ct * 128 + w * 32 + ni * 16 + lr;
                bfr[ni] = *reinterpret_cast<const bf16x8*>(&wbBT[(size_t)col * 128 + k * 32 + lg * 8]);
            }
            bf16x8 ah[4];
            #pragma unroll
            for (int mi = 0; mi < 4; ++mi)
                ah[mi] = *reinterpret_cast<const bf16x8*>(&xpH[(mi * 16 + lr) * 136 + k * 32 + lg * 8]);
            #pragma unroll
            for (int ni = 0; ni < 2; ++ni)
                #pragma unroll
                for (int mi = 0; mi < 4; ++mi)
                    accT[ni][mi] = __builtin_amdgcn_mfma_f32_16x16x32_bf16(bfr[ni], ah[mi], accT[ni][mi], 0, 0, 0);
        }
        #pragma unroll
        for (int ni = 0; ni < 2; ++ni) {
            int colg = w * 32 + ni * 16 + lg * 4;
            #pragma unroll
            for (int mi = 0; mi < 4; ++mi) {
                unsigned pk = pack4_fp8(accT[ni][mi][0] + wl1[(colg + 0) * 8 + ct],
                                        accT[ni][mi][1] + wl1[(colg + 1) * 8 + ct],
                                        accT[ni][mi][2] + wl1[(colg + 2) * 8 + ct],
                                        accT[ni][mi][3] + wl1[(colg + 3) * 8 + ct]);
                *reinterpret_cast<unsigned*>(&yb[(mi * 16 + lr) * 136 + colg]) = pk;
            }
        }
        __syncthreads();
        #pragma unroll
        for (int pass = 0; pass < 2; ++pass) {
            int flat = pass * 4096 + tid * 16;
            int rl = flat >> 7, cs = flat & 127;
            int row = row0 + rl;
            if (row < M) {
                uchar16v vv = *reinterpret_cast<const uchar16v*>(&yb[rl * 136 + cs]);
                *reinterpret_cast<uchar16v*>(&Y[(size_t)row * 1024 + ct * 128 + cs]) = vv;
            }
        }
        __syncthreads();
    }
}

// ========== fused edge kernel v7: 2 edges/wave for load ILP ==========
__global__ __launch_bounds__(256) void edge_fused3(const float* __restrict__ xpf,
                                                   const short* __restrict__ ep,
                                                   const unsigned char* __restrict__ Y,
                                                   const int* __restrict__ ei,
                                                   const float* __restrict__ u,
                                                   const float* __restrict__ wl2g,
                                                   float* __restrict__ agg, int E) {
    __shared__ float swl[128][9];
    for (int i = threadIdx.x; i < 1024; i += 256) swl[i >> 3][i & 7] = wl2g[i];
    __syncthreads();
    int w = threadIdx.x >> 6;
    int l = threadIdx.x & 63;
    int s = l & 7, c0 = (l >> 3) * 16;
    int e0 = blockIdx.x * 8 + w;
    int e1 = e0 + 4;
    bool ok0 = e0 < E, ok1 = e1 < E;
    int src0 = ok0 ? ei[e0] : 0, dst0 = ok0 ? ei[E + e0] : 0;
    int src1 = ok1 ? ei[e1] : 0, dst1 = ok1 ? ei[E + e1] : 0;

    uchar16v yv0 = *reinterpret_cast<const uchar16v*>(Y + (size_t)src0 * 1024 + s * 128 + c0);
    uchar16v yv1 = *reinterpret_cast<const uchar16v*>(Y + (size_t)src1 * 1024 + s * 128 + c0);
    const float* xi0 = xpf + (size_t)dst0 * 128 + c0;
    const float* xi1 = xpf + (size_t)dst1 * 128 + c0;
    f32x4 xa0 = *reinterpret_cast<const f32x4*>(xi0);
    f32x4 xb0 = *reinterpret_cast<const f32x4*>(xi0 + 4);
    f32x4 xc0 = *reinterpret_cast<const f32x4*>(xi0 + 8);
    f32x4 xd0 = *reinterpret_cast<const f32x4*>(xi0 + 12);
    f32x4 xa1 = *reinterpret_cast<const f32x4*>(xi1);
    f32x4 xb1 = *reinterpret_cast<const f32x4*>(xi1 + 4);
    f32x4 xc1 = *reinterpret_cast<const f32x4*>(xi1 + 8);
    f32x4 xd1 = *reinterpret_cast<const f32x4*>(xi1 + 12);
    short16v ev0 = *reinterpret_cast<const short16v*>(ep + (size_t)e0 * 128 + c0);
    short16v ev1 = *reinterpret_cast<const short16v*>(ep + (size_t)(ok1 ? e1 : e0) * 128 + c0);
    float xj00 = xpf[(size_t)src0 * 128 + l];
    float xj01 = xpf[(size_t)src0 * 128 + l + 64];
    float xj10 = xpf[(size_t)src1 * 128 + l];
    float xj11 = xpf[(size_t)src1 * 128 + l + 64];
    float u0 = u[(size_t)src0 * 8 + s];
    float u1 = u[(size_t)src1 * 8 + s];
    float em00 = bf2f(ep[(size_t)e0 * 128 + l]);
    float em01 = bf2f(ep[(size_t)e0 * 128 + l + 64]);
    float em10 = bf2f(ep[(size_t)(ok1 ? e1 : e0) * 128 + l]);
    float em11 = bf2f(ep[(size_t)(ok1 ? e1 : e0) * 128 + l + 64]);

    const int* yw0 = reinterpret_cast<const int*>(&yv0);
    const int* yw1 = reinterpret_cast<const int*>(&yv1);
    float p0 = 0.f, p1 = 0.f;
    #pragma unroll
    for (int q = 0; q < 4; ++q) {
        f32x2 a0 = unpack2_fp8<false>(yw0[q]);
        f32x2 b0 = unpack2_fp8<true>(yw0[q]);
        f32x2 a1 = unpack2_fp8<false>(yw1[q]);
        f32x2 b1 = unpack2_fp8<true>(yw1[q]);
        const f32x4* xq0 = (q == 0) ? &xa0 : (q == 1) ? &xb0 : (q == 2) ? &xc0 : &xd0;
        const f32x4* xq1 = (q == 0) ? &xa1 : (q == 1) ? &xb1 : (q == 2) ? &xc1 : &xd1;
        p0 += (*xq0)[0] * a0[0] + (*xq0)[1] * a0[1] + (*xq0)[2] * b0[0] + (*xq0)[3] * b0[1];
        p1 += (*xq1)[0] * a1[0] + (*xq1)[1] * a1[1] + (*xq1)[2] * b1[0] + (*xq1)[3] * b1[1];
    }
    #pragma unroll
    for (int j = 0; j < 8; ++j) {
        float w0 = swl[c0 + j][s], w1 = swl[c0 + 8 + j][s];
        p0 += bf2f(ev0[j]) * w0 + bf2f(ev0[8 + j]) * w1;
        p1 += bf2f(ev1[j]) * w0 + bf2f(ev1[8 + j]) * w1;
    }
    p0 += __shfl_xor(p0, 8); p0 += __shfl_xor(p0, 16); p0 += __shfl_xor(p0, 32);
    p1 += __shfl_xor(p1, 8); p1 += __shfl_xor(p1, 16); p1 += __shfl_xor(p1, 32);
    float alpha0 = tanhf(p0 + u0);
    float alpha1 = tanhf(p1 + u1);
    float a00 = __shfl(alpha0, l >> 4);
    float a01 = __shfl(alpha0, 4 + (l >> 4));
    float a10 = __shfl(alpha1, l >> 4);
    float a11 = __shfl(alpha1, 4 + (l >> 4));
    if (ok0) {
        atomicAdd(&agg[(size_t)dst0 * 128 + l],      fmaxf(xj00, em00) * a00);
        atomicAdd(&agg[(size_t)dst0 * 128 + l + 64], fmaxf(xj01, em01) * a01);
    }
    if (ok1) {
        atomicAdd(&agg[(size_t)dst1 * 128 + l],      fmaxf(xj10, em10) * a10);
        atomicAdd(&agg[(size_t)dst1 * 128 + l + 64], fmaxf(xj11, em11) * a11);
    }
}

// ========== gate GEMM v2: 64-row tiles, split-3, K=256 combined, in place ==========
__global__ __launch_bounds__(256) void gate_gemm_split(float* __restrict__ h,
                                                       const float* __restrict__ aggv,
                                                       const short* __restrict__ BTh,
                                                       const short* __restrict__ BTl,
                                                       const float* __restrict__ gb,
                                                       int M) {
    __shared__ short Ah[64][40];
    __shared__ short Al[64][40];
    __shared__ short Bh[128][40];
    __shared__ short Bl[128][40];
    const int tid = threadIdx.x;
    const int row0 = blockIdx.x * 64;
    const int lane = tid & 63, w = tid >> 6;
    const int lr = lane & 15, lg = lane >> 4;
    f32x4 acc[4][2] = {};

    for (int k0 = 0; k0 < 256; k0 += 32) {
        int sec = k0 >> 7;
        #pragma unroll
        for (int i = 0; i < 2; ++i) {
            int idx = i * 256 + tid;
            int r = idx >> 3, q = idx & 7;
            int gr = row0 + r;
            int ks = (k0 & 127) + q * 4;
            f32x4 v;
            if (gr < M) {
                if (sec == 0) {
                    v = *reinterpret_cast<const f32x4*>(&h[(size_t)gr * 128 + ks]);
                } else {
                    f32x4 a = *reinterpret_cast<const f32x4*>(&aggv[(size_t)gr * 128 + ks]);
                    #pragma unroll
                    for (int j = 0; j < 4; ++j) v[j] = fmaxf(a[j], 0.f);
                }
            } else {
                #pragma unroll
                for (int j = 0; j < 4; ++j) v[j] = 0.f;
            }
            short4v hh, ll;
            #pragma unroll
            for (int j = 0; j < 4; ++j) {
                hh[j] = f2bf(v[j]);
                ll[j] = f2bf(v[j] - bf2f(hh[j]));
            }
            *reinterpret_cast<short4v*>(&Ah[r][q * 4]) = hh;
            *reinterpret_cast<short4v*>(&Al[r][q * 4]) = ll;
        }
        #pragma unroll
        for (int i = 0; i < 4; ++i) {
            int idx = i * 256 + tid;
            int r = idx >> 3, q = idx & 7;
            short4v uu = *reinterpret_cast<const short4v*>(&BTh[(size_t)r * 256 + k0 + q * 4]);
            short4v ul = *reinterpret_cast<const short4v*>(&BTl[(size_t)r * 256 + k0 + q * 4]);
            *reinterpret_cast<short4v*>(&Bh[r][q * 4]) = uu;
            *reinterpret_cast<short4v*>(&Bl[r][q * 4]) = ul;
        }
        __syncthreads();
        bf16x8 afh[4], afl[4], bfh[2], bfl[2];
        #pragma unroll
        for (int mi = 0; mi < 4; ++mi) {
            afh[mi] = *reinterpret_cast<const bf16x8*>(&Ah[mi * 16 + lr][lg * 8]);
            afl[mi] = *reinterpret_cast<const bf16x8*>(&Al[mi * 16 + lr][lg * 8]);
        }
        #pragma unroll
        for (int ni = 0; ni < 2; ++ni) {
            bfh[ni] = *reinterpret_cast<const bf16x8*>(&Bh[w * 32 + ni * 16 + lr][lg * 8]);
            bfl[ni] = *reinterpret_cast<const bf16x8*>(&Bl[w * 32 + ni * 16 + lr][lg * 8]);
        }
        #pragma unroll
        for (int mi = 0; mi < 4; ++mi)
            #pragma unroll
            for (int ni = 0; ni < 2; ++ni) {
                acc[mi][ni] = __builtin_amdgcn_mfma_f32_16x16x32_bf16(afh[mi], bfh[ni], acc[mi][ni], 0, 0, 0);
                acc[mi][ni] = __builtin_amdgcn_mfma_f32_16x16x32_bf16(afl[mi], bfh[ni], acc[mi][ni], 0, 0, 0);
                acc[mi][ni] = __builtin_amdgcn_mfma_f32_16x16x32_bf16(afh[mi], bfl[ni], acc[mi][ni], 0, 0, 0);
            }
        __syncthreads();
    }

    #pragma unroll
    for (int mi = 0; mi < 4; ++mi) {
        #pragma unroll
        for (int ni = 0; ni < 2; ++ni) {
            int col = w * 32 + ni * 16 + lr;
            float gbv = gb[col];
            #pragma unroll
            for (int r = 0; r < 4; ++r) {
                int row = row0 + mi * 16 + lg * 4 + r;
                if (row >= M) continue;
                float beta = fmaxf(acc[mi][ni][r] + gbv, 0.f);
                float hv = h[(size_t)row * 128 + col];
                float hh = fmaxf(aggv[(size_t)row * 128 + col], 0.f);
                h[(size_t)row * 128 + col] = beta * hv + (1.f - beta) * hh;
            }
        }
    }
}

// ========== batch norm ==========
__global__ void bn_stats(const float* __restrict__ z, float* __restrict__ gsum,
                         float* __restrict__ gsq, int M) {
    int c = threadIdx.x & 127;
    int rr = threadIdx.x >> 7;
    float s = 0.f, q = 0.f;
    for (int r = blockIdx.x * 2 + rr; r < M; r += gridDim.x * 2) {
        float v = z[(size_t)r * 128 + c];
        s += v; q += v * v;
    }
    __shared__ float ls[256], lq[256];
    ls[threadIdx.x] = s; lq[threadIdx.x] = q;
    __syncthreads();
    if (threadIdx.x < 128) {
        atomicAdd(&gsum[c], ls[threadIdx.x] + ls[threadIdx.x + 128]);
        atomicAdd(&gsq[c],  lq[threadIdx.x] + lq[threadIdx.x + 128]);
    }
}

__global__ void bn_apply(float* __restrict__ z, const float* __restrict__ gsum,
                         const float* __restrict__ gsq, const float* __restrict__ g,
                         const float* __restrict__ b, int M) {
    size_t total = (size_t)M * 128;
    for (size_t idx = (size_t)blockIdx.x * 256 + threadIdx.x; idx < total;
         idx += (size_t)gridDim.x * 256) {
        int c = idx & 127;
        float mu = gsum[c] / (float)M;
        float var = gsq[c] / (float)M - mu * mu;
        float rs = rsqrtf(var + EPS);
        float v = (z[idx] - mu) * rs * g[c] + b[c];
        z[idx] = fmaxf(v, 0.f);
    }
}

__global__ void bn_stats_bf(const short* __restrict__ z, float* __restrict__ gsum,
                            float* __restrict__ gsq, int M) {
    int c = threadIdx.x & 127;
    int rr = threadIdx.x >> 7;
    float s = 0.f, q = 0.f;
    for (int r = blockIdx.x * 2 + rr; r < M; r += gridDim.x * 2) {
        float v = bf2f(z[(size_t)r * 128 + c]);
        s += v; q += v * v;
    }
    __shared__ float ls[256], lq[256];
    ls[threadIdx.x] = s; lq[threadIdx.x] = q;
    __syncthreads();
    if (threadIdx.x < 128) {
        atomicAdd(&gsum[c], ls[threadIdx.x] + ls[threadIdx.x + 128]);
        atomicAdd(&gsq[c],  lq[threadIdx.x] + lq[threadIdx.x + 128]);
    }
}

__global__ void bn_apply_bf(short* __restrict__ z, const float* __restrict__ gsum,
                            const float* __restrict__ gsq, const float* __restrict__ g,
                            const float* __restrict__ b, int M) {
    size_t total = (size_t)M * 128;
    for (size_t idx = (size_t)blockIdx.x * 256 + threadIdx.x; idx < total;
         idx += (size_t)gridDim.x * 256) {
        int c = idx & 127;
        float mu = gsum[c] / (float)M;
        float var = gsq[c] / (float)M - mu * mu;
        float rs = rsqrtf(var + EPS);
        float v = (bf2f(z[idx]) - mu) * rs * g[c] + b[c];
        z[idx] = f2bf(fmaxf(v, 0.f));
    }
}

// ========== prep ==========
__global__ void transpose_split(const float* __restrict__ in, short* __restrict__ outh,
                                short* __restrict__ outl, int K, int N) {
    int idx = blockIdx.x * 256 + threadIdx.x;
    if (idx >= K * N) return;
    int nI = idx / K, k = idx - nI * K;
    float v = in[(size_t)k * N + nI];
    short h = f2bf(v);
    outh[idx] = h;
    outl[idx] = f2bf(v - bf2f(h));
}

__global__ void cvt_f2b(const float* __restrict__ in, short* __restrict__ out, int n) {
    int i = blockIdx.x * 256 + threadIdx.x;
    if (i < n) out[i] = f2bf(in[i]);
}

__global__ void gate_combine_split(const float* __restrict__ gw, short* __restrict__ BTh,
                                   short* __restrict__ BTl) {
    int idx = blockIdx.x * 256 + threadIdx.x;
    if (idx >= 128 * 256) return;
    int n = idx >> 8, k = idx & 255;
    float v;
    if (k < 128) v = gw[(size_t)k * 128 + n] + gw[(size_t)(256 + k) * 128 + n];
    else {
        int kk = k - 128;
        v = gw[(size_t)(128 + kk) * 128 + n] - gw[(size_t)(256 + kk) * 128 + n];
    }
    short h = f2bf(v);
    BTh[idx] = h;
    BTl[idx] = f2bf(v - bf2f(h));
}

__global__ void build_wm(const float* __restrict__ wsrc, float* __restrict__ wm) {
    int idx = blockIdx.x * 256 + threadIdx.x;
    if (idx >= 128 * 128) return;
    int d = idx >> 7, c = idx & 127;
    float s = 0.f;
    #pragma unroll
    for (int h = 0; h < 8; ++h) s += wsrc[(size_t)d * 1024 + h * 128 + c];
    wm[idx] = s * 0.125f;
}

__global__ void perm_build(const int* __restrict__ ci, int* __restrict__ perm, int NF) {
    int i = blockIdx.x * 256 + threadIdx.x;
    if (i >= NF) return;
    int c = ci[i];
    if (i == 0 || ci[i - 1] != c) perm[c] = i;
}

__global__ void seg_pool(const float* __restrict__ fx, const int* __restrict__ perm,
                         float* __restrict__ pool, int F, int NF) {
    int idx = blockIdx.x * 256 + threadIdx.x;
    if (idx >= F * 128) return;
    int f = idx >> 7, c = idx & 127;
    int s = perm[f];
    int e = (f + 1 < F) ? perm[f + 1] : NF;
    float acc = 0.f;
    for (int i = s; i < e; ++i) acc += fx[(size_t)i * 128 + c];
    pool[idx] = fmaxf(acc, 0.f);
}

// ========== output ==========
__global__ __launch_bounds__(256) void out_phase1(const float* __restrict__ h,
                                                  const float* __restrict__ out_w,
                                                  const float* __restrict__ out_b,
                                                  const float* __restrict__ gat_bias,
                                                  float* __restrict__ out, int M) {
    int n = blockIdx.x * 4 + (threadIdx.x >> 6);
    if (n >= M) return;
    int l = threadIdx.x & 63;
    float p = fmaxf(h[(size_t)n * 128 + l], 0.f) * out_w[l]
            + fmaxf(h[(size_t)n * 128 + l + 64], 0.f) * out_w[l + 64];
    p += fmaxf(gat_bias[l], 0.f) * out_w[128 + l]
       + fmaxf(gat_bias[l + 64], 0.f) * out_w[128 + l + 64];
    #pragma unroll
    for (int off = 32; off; off >>= 1) p += __shfl_xor(p, off);
    if (l == 0) out[n] = p + out_b[0];
}

__global__ __launch_bounds__(256) void out_phase2(const float* __restrict__ fmv,
                                                  const int* __restrict__ perm,
                                                  const float* __restrict__ out_w,
                                                  const float* __restrict__ gat_bias,
                                                  float* __restrict__ out, int F) {
    int f = blockIdx.x * 4 + (threadIdx.x >> 6);
    if (f >= F) return;
    int l = threadIdx.x & 63;
    float p = fmv[(size_t)f * 128 + l] * out_w[128 + l]
            + fmv[(size_t)f * 128 + l + 64] * out_w[128 + l + 64];
    float b = fmaxf(gat_bias[l], 0.f) * out_w[128 + l]
            + fmaxf(gat_bias[l + 64], 0.f) * out_w[128 + l + 64];
    float d = p - b;
    #pragma unroll
    for (int off = 32; off; off >>= 1) d += __shfl_xor(d, off);
    if (l == 0) out[perm[f]] += d;
}

// ========== host ==========
extern "C" void kernel_launch(void* const* d_in, const int* in_sizes, int n_in,
                              void* d_out, int out_size, void* d_ws, size_t ws_size,
                              hipStream_t stream) {
    const int N = 50000, E = 100000, NF = 20000, EF = 40000, F = 10000;

    const float* x          = (const float*)d_in[0];
    const float* edge_attr  = (const float*)d_in[1];
    const float* frag_x     = (const float*)d_in[2];
    const float* frag_ea    = (const float*)d_in[3];
    const float* la_w = (const float*)d_in[4];
    const float* la_b = (const float*)d_in[5];
    const float* lb_w = (const float*)d_in[6];
    const float* lb_b = (const float*)d_in[7];
    const float* bn1_g = (const float*)d_in[8];
    const float* bn1_b = (const float*)d_in[9];
    const float* bn2_g = (const float*)d_in[10];
    const float* bn2_b = (const float*)d_in[11];
    const float* wn = (const float*)d_in[12];
    const float* wb = (const float*)d_in[13];
    const float* wl = (const float*)d_in[14];
    const float* wlb = (const float*)d_in[15];
    const float* gate_w = (const float*)d_in[16];
    const float* gate_b = (const float*)d_in[17];
    const float* gat_wsrc = (const float*)d_in[18];
    const float* gat_bias = (const float*)d_in[22];
    const float* out_w = (const float*)d_in[23];
    const float* out_b = (const float*)d_in[24];
    const int* edge_index = (const int*)d_in[25];
    const int* frag_edge_index = (const int*)d_in[26];
    const int* cluster_index = (const int*)d_in[27];

    char* p = (char*)d_ws;
    auto alloc = [&](size_t bytes) { char* r = p; p += (bytes + 255) & ~(size_t)255; return (void*)r; };
    float* hA    = (float*)alloc((size_t)N * 128 * 4);
    short* ea1   = (short*)alloc((size_t)E * 128 * 2);
    float* xpf   = (float*)alloc((size_t)N * 128 * 4);
    short* ep    = (short*)alloc((size_t)E * 128 * 2);
    unsigned char* Y = (unsigned char*)alloc((size_t)N * 1024);
    float* agg   = (float*)alloc((size_t)N * 128 * 4);
    float* ubuf  = (float*)alloc((size_t)N * 8 * 4);
    short* la_wTh = (short*)alloc(128 * 128 * 2);
    short* la_wTl = (short*)alloc(128 * 128 * 2);
    short* lb_wTh = (short*)alloc(128 * 16 * 2);
    short* lb_wTl = (short*)alloc(128 * 16 * 2);
    short* wnTh   = (short*)alloc(3 * 128 * 128 * 2);
    short* wnTl   = (short*)alloc(3 * 128 * 128 * 2);
    short* wbH    = (short*)alloc(3 * 1024 * 128 * 2);
    short* gate2Th = (short*)alloc(128 * 256 * 2);
    short* gate2Tl = (short*)alloc(128 * 256 * 2);
    float* wmF    = (float*)alloc(128 * 128 * 4);
    short* wmTh   = (short*)alloc(128 * 128 * 2);
    short* wmTl   = (short*)alloc(128 * 128 * 2);
    float* stats  = (float*)alloc(256 * 4);
    char* yq = (char*)Y;
    float* fpool = (float*)yq;              yq += (size_t)F * 128 * 4;
    float* fmv   = (float*)yq;              yq += (size_t)F * 128 * 4;
    int*   perm  = (int*)yq;

    auto cdiv = [](int a, int b) { return (a + b - 1) / b; };

    // ---- weight prep ----
    transpose_split<<<cdiv(128 * 128, 256), 256, 0, stream>>>(la_w, la_wTh, la_wTl, 128, 128);
    transpose_split<<<cdiv(16 * 128, 256), 256, 0, stream>>>(lb_w, lb_wTh, lb_wTl, 16, 128);
    for (int l = 0; l < 3; ++l)
        transpose_split<<<cdiv(128 * 128, 256), 256, 0, stream>>>(
            wn + (size_t)l * 16384, wnTh + (size_t)l * 16384, wnTl + (size_t)l * 16384, 128, 128);
    cvt_f2b<<<cdiv(3 * 1024 * 128, 256), 256, 0, stream>>>(wb, wbH, 3 * 1024 * 128);
    gate_combine_split<<<cdiv(128 * 256, 256), 256, 0, stream>>>(gate_w, gate2Th, gate2Tl);
    build_wm<<<cdiv(128 * 128, 256), 256, 0, stream>>>(gat_wsrc, wmF);
    transpose_split<<<cdiv(128 * 128, 256), 256, 0, stream>>>(wmF, wmTh, wmTl, 128, 128);

    auto run_layer = [&](float* h, const short* ea_buf, const int* ei, int Mn, int Me, int layer) {
        const short* wnTh_l = wnTh + (size_t)layer * 16384;
        const short* wnTl_l = wnTl + (size_t)layer * 16384;
        const short* wb_l   = wbH + (size_t)layer * 131072;
        const float* wl_l   = wl + (size_t)layer * 384 * 8;
        const float* wlb_l  = wlb + (size_t)layer * 8;
        fused_xpy<<<cdiv(Mn, 64), 256, 0, stream>>>(h, wnTh_l, wnTl_l, wb_l, wl_l,
                                                    wl_l + 256 * 8, wlb_l, xpf, ubuf, Y, agg, Mn);
        ep_gemm64<<<cdiv(Me, 64), 256, 0, stream>>>(ea_buf, wnTh_l, ep, Me);
        edge_fused3<<<cdiv(Me, 8), 256, 0, stream>>>(xpf, ep, Y, ei, ubuf, wl_l + 128 * 8, agg, Me);
        gate_gemm_split<<<cdiv(Mn, 64), 256, 0, stream>>>(h, agg, gate2Th, gate2Tl, gate_b, Mn);
    };

    // ---- atom path ----
    gemm_split<3, 0, 0><<<dim3(1, cdiv(N, 128)), 256, 0, stream>>>(x, la_wTh, la_wTl, la_b, hA, nullptr, N, 128, 128);
    hipMemsetAsync(stats, 0, 1024, stream);
    bn_stats<<<256, 256, 0, stream>>>(hA, stats, stats + 128, N);
    bn_apply<<<2048, 256, 0, stream>>>(hA, stats, stats + 128, bn1_g, bn1_b, N);

    gemm_split<3, 0, 1><<<dim3(1, cdiv(E, 128)), 256, 0, stream>>>(edge_attr, lb_wTh, lb_wTl, lb_b, ea1, nullptr, E, 128, 16);
    hipMemsetAsync(stats, 0, 1024, stream);
    bn_stats_bf<<<256, 256, 0, stream>>>(ea1, stats, stats + 128, E);
    bn_apply_bf<<<2048, 256, 0, stream>>>(ea1, stats, stats + 128, bn2_g, bn2_b, E);

    for (int l = 0; l < 3; ++l) run_layer(hA, ea1, edge_index, N, E, l);
    out_phase1<<<cdiv(N, 4), 256, 0, stream>>>(hA, out_w, out_b, gat_bias, (float*)d_out, N);

    // ---- fragment path ----
    gemm_split<3, 1, 0><<<dim3(1, cdiv(NF, 128)), 256, 0, stream>>>(frag_x, la_wTh, la_wTl, la_b, hA, nullptr, NF, 128, 128);

    gemm_split<3, 0, 1><<<dim3(1, cdiv(EF, 128)), 256, 0, stream>>>(frag_ea, lb_wTh, lb_wTl, lb_b, ea1, nullptr, EF, 128, 16);
    hipMemsetAsync(stats, 0, 1024, stream);
    bn_stats_bf<<<256, 256, 0, stream>>>(ea1, stats, stats + 128, EF);
    bn_apply_bf<<<2048, 256, 0, stream>>>(ea1, stats, stats + 128, bn2_g, bn2_b, EF);

    for (int l = 0; l < 3; ++l) run_layer(hA, ea1, frag_edge_index, NF, EF, l);

    perm_build<<<cdiv(NF, 256), 256, 0, stream>>>(cluster_index, perm, NF);
    seg_pool<<<cdiv(F * 128, 256), 256, 0, stream>>>(hA, perm, fpool, F, NF);
    gemm_split<3, 1, 0><<<dim3(1, cdiv(F, 128)), 256, 0, stream>>>(fpool, wmTh, wmTl, gat_bias, fmv, nullptr, F, 128, 128);
    out_phase2<<<cdiv(F, 4), 256, 0, stream>>>(fmv, perm, out_w, gat_bias, (float*)d_out, F);
}